// Round 14
// baseline (10061.504 us; speedup 1.0000x reference)
//
#include <hip/hip_runtime.h>

#define DEVI __device__ __forceinline__

typedef float  f32x4  __attribute__((ext_vector_type(4)));
typedef __bf16 bf16x8 __attribute__((ext_vector_type(8)));
typedef unsigned short u16x8 __attribute__((ext_vector_type(8)));

// ---------- helpers ----------
DEVI unsigned short f2bf(float f) {
    unsigned u = __builtin_bit_cast(unsigned, f);
    unsigned r = (u + 0x7fffu + ((u >> 16) & 1u)) >> 16;
    return (unsigned short)r;
}
DEVI float bf2f(unsigned short s) {
    return __builtin_bit_cast(float, (unsigned)s << 16);
}
DEVI u16x8 pack8(float4 a, float4 b) {
    u16x8 p;
    p[0] = f2bf(a.x); p[1] = f2bf(a.y); p[2] = f2bf(a.z); p[3] = f2bf(a.w);
    p[4] = f2bf(b.x); p[5] = f2bf(b.y); p[6] = f2bf(b.z); p[7] = f2bf(b.w);
    return p;
}
DEVI f32x4 mfma16(u16x8 a, u16x8 b, f32x4 c) {
    return __builtin_amdgcn_mfma_f32_16x16x32_bf16(
        __builtin_bit_cast(bf16x8, a), __builtin_bit_cast(bf16x8, b), c, 0, 0, 0);
}
DEVI float sigm(float x)   { return 1.f / (1.f + __expf(-x)); }
DEVI float tanh_f(float x) { return 1.f - 2.f / (1.f + __expf(2.f * x)); }

// dims
#define Hh 256
#define Bb 64
#define Tt 1024

// ---------- K0: hp[b][k] = hidden[b] . W_w[k][0:256]; block 0 also folds biases ----------
__global__ __launch_bounds__(256) void hp_kernel(const float* __restrict__ hid,
                                                 const float* __restrict__ Ww,
                                                 const float* __restrict__ b_ir,
                                                 const float* __restrict__ b_hr,
                                                 const float* __restrict__ b_iz,
                                                 const float* __restrict__ b_hz,
                                                 float* __restrict__ hp,
                                                 float* __restrict__ cb) {
    int b = blockIdx.x, k = threadIdx.x;
    if (b == 0) {  // fused bias_prep (saves a launch)
        cb[k] = b_ir[k] + b_hr[k];
        cb[256 + k] = b_iz[k] + b_hz[k];
    }
    __shared__ __align__(16) float hs[Hh];
    hs[k] = hid[b * Hh + k];
    __syncthreads();
    const float4* w4 = (const float4*)(Ww + (size_t)k * 512);
    const float4* h4 = (const float4*)hs;
    float acc = 0.f;
#pragma unroll 8
    for (int i = 0; i < 64; i++) {
        float4 a = w4[i], x = h4[i];
        acc += a.x * x.x + a.y * x.y + a.z * x.z + a.w * x.w;
    }
    hp[b * Hh + k] = acc;
}

// ---------- GEMM 128x128 tile (EPI0 / EPI2): 8 waves in 2x4, 512 MFMA/block ----------
template <int EPI, bool ABF16>
__global__ __launch_bounds__(512) void gemm128(
    const void* __restrict__ Aab,
    const float* __restrict__ W0, const float* __restrict__ W1, const float* __restrict__ W2,
    int wstride, int wcoloff,
    const float* __restrict__ bv0, const float* __restrict__ bv1, const float* __restrict__ bv2,
    const float* __restrict__ hp, const float* __restrict__ Wb,
    void* __restrict__ outv) {
    __shared__ __align__(16) unsigned short As[128 * 256];  // 64KB
    __shared__ __align__(16) unsigned short Bs[128 * 256];  // 64KB (128KB total: 1 WG/CU)

    int tid = threadIdx.x;
    int bx = blockIdx.x, by = blockIdx.y;
    int mat = (EPI == 2) ? (by >> 1) : 0;
    int cb  = (EPI == 2) ? (by & 1) : by;
    int rowBase = bx * 128, colBase = cb * 128;
    const float* W  = (mat == 0) ? W0 : ((mat == 1) ? W1 : W2);
    const float* bv = (mat == 0) ? bv0 : ((mat == 1) ? bv1 : bv2);

    if (ABF16) {
        const unsigned short* A = (const unsigned short*)Aab;
#pragma unroll
        for (int i = 0; i < 8; i++) {
            int idx = i * 512 + tid, r = idx >> 5, g = idx & 31, gs = g ^ (r & 7);
            *(uint4*)&As[r * 256 + gs * 8] =
                *(const uint4*)(A + (((size_t)(rowBase + r)) << 8) + g * 8);
        }
    } else {
        const float* A = (const float*)Aab;
#pragma unroll
        for (int i = 0; i < 8; i++) {
            int idx = i * 512 + tid, r = idx >> 5, g = idx & 31, gs = g ^ (r & 7);
            const float* s = A + (((size_t)(rowBase + r)) << 8) + g * 8;
            float4 f0 = *(const float4*)s, f1 = *(const float4*)(s + 4);
            *(u16x8*)&As[r * 256 + gs * 8] = pack8(f0, f1);
        }
    }
#pragma unroll
    for (int i = 0; i < 8; i++) {
        int idx = i * 512 + tid, r = idx >> 5, g = idx & 31, gs = g ^ (r & 7);
        const float* s = W + (size_t)(colBase + r) * wstride + wcoloff + g * 8;
        float4 f0 = *(const float4*)s, f1 = *(const float4*)(s + 4);
        *(u16x8*)&Bs[r * 256 + gs * 8] = pack8(f0, f1);
    }
    __syncthreads();

    int wid = tid >> 6, lane = tid & 63, l15 = lane & 15, grp = lane >> 4;
    int wr = (wid >> 2) * 64, wc = (wid & 3) * 32;   // wave tile: 64 rows x 32 cols
    f32x4 acc[4][2] = {};
#pragma unroll
    for (int kc = 0; kc < 8; kc++) {
        u16x8 a[4], bb[2];
#pragma unroll
        for (int rt = 0; rt < 4; rt++) {
            int r = wr + rt * 16 + l15;
            int gs = (kc * 4 + grp) ^ (r & 7);
            a[rt] = *(const u16x8*)&As[r * 256 + gs * 8];
        }
#pragma unroll
        for (int ct = 0; ct < 2; ct++) {
            int r = wc + ct * 16 + l15;
            int gs = (kc * 4 + grp) ^ (r & 7);
            bb[ct] = *(const u16x8*)&Bs[r * 256 + gs * 8];
        }
#pragma unroll
        for (int rt = 0; rt < 4; rt++)
#pragma unroll
            for (int ct = 0; ct < 2; ct++)
                acc[rt][ct] = mfma16(a[rt], bb[ct], acc[rt][ct]);
    }
#pragma unroll
    for (int rt = 0; rt < 4; rt++)
#pragma unroll
        for (int ct = 0; ct < 2; ct++)
#pragma unroll
            for (int i = 0; i < 4; i++) {
                int rl = wr + rt * 16 + grp * 4 + i;
                int cl = wc + ct * 16 + l15;
                size_t r = (size_t)rowBase + rl;
                int c = colBase + cl;
                float v = acc[rt][ct][i];
                if (EPI == 0) {
                    v = tanh_f(v + hp[(r >> 10) * 256 + c] + Wb[c]);
                    ((unsigned short*)outv)[r * 256 + c] = f2bf(v);
                } else {
                    ((unsigned short*)outv)[(size_t)mat * 16777216 + r * 256 + c] =
                        f2bf(v + bv[c]);
                }
            }
}

// ---------- GEMM 128x64 (EPI1 only): scores + fused softmax pass1 ----------
__global__ __launch_bounds__(512) void gemm_k1(
    const void* __restrict__ Aab,
    const float* __restrict__ W0, int wstride, int wcoloff,
    const float* __restrict__ bv0,
    float* __restrict__ pms,
    void* __restrict__ outv) {
    __shared__ __align__(16) unsigned short As[128 * 256];
    __shared__ __align__(16) unsigned short Bs[64 * 256];
    __shared__ float sredm[8][2][16], sredS[8][2][16];

    int tid = threadIdx.x;
    int bx = blockIdx.x, by = blockIdx.y;
    int rowBase = bx * 128, colBase = by * 64;
    const float* W = W0;
    const float* bv = bv0;

    const unsigned short* A = (const unsigned short*)Aab;
#pragma unroll
    for (int i = 0; i < 8; i++) {
        int idx = i * 512 + tid, r = idx >> 5, g = idx & 31, gs = g ^ (r & 7);
        *(uint4*)&As[r * 256 + gs * 8] =
            *(const uint4*)(A + (((size_t)(rowBase + r)) << 8) + g * 8);
    }
#pragma unroll
    for (int i = 0; i < 4; i++) {
        int idx = i * 512 + tid, r = idx >> 5, g = idx & 31, gs = g ^ (r & 7);
        const float* s = W + (size_t)(colBase + r) * wstride + wcoloff + g * 8;
        float4 f0 = *(const float4*)s, f1 = *(const float4*)(s + 4);
        *(u16x8*)&Bs[r * 256 + gs * 8] = pack8(f0, f1);
    }
    __syncthreads();

    int wid = tid >> 6, lane = tid & 63, l15 = lane & 15, grp = lane >> 4;
    int wr = (wid >> 1) * 32, wc = (wid & 1) * 32;
    f32x4 acc[2][2] = {};
#pragma unroll
    for (int kc = 0; kc < 8; kc++) {
        u16x8 a[2], bb[2];
#pragma unroll
        for (int rt = 0; rt < 2; rt++) {
            int r = wr + rt * 16 + l15;
            int gs = (kc * 4 + grp) ^ (r & 7);
            a[rt] = *(const u16x8*)&As[r * 256 + gs * 8];
        }
#pragma unroll
        for (int ct = 0; ct < 2; ct++) {
            int r = wc + ct * 16 + l15;
            int gs = (kc * 4 + grp) ^ (r & 7);
            bb[ct] = *(const u16x8*)&Bs[r * 256 + gs * 8];
        }
#pragma unroll
        for (int rt = 0; rt < 2; rt++)
#pragma unroll
            for (int ct = 0; ct < 2; ct++)
                acc[rt][ct] = mfma16(a[rt], bb[ct], acc[rt][ct]);
    }
    float vv[2][2][4];
#pragma unroll
    for (int rt = 0; rt < 2; rt++)
#pragma unroll
        for (int ct = 0; ct < 2; ct++)
#pragma unroll
            for (int i = 0; i < 4; i++) {
                int rl = wr + rt * 16 + grp * 4 + i;
                int cl = wc + ct * 16 + l15;
                size_t r = (size_t)rowBase + rl;
                int c = colBase + cl;
                float sc = acc[rt][ct][i] + bv[c];
                vv[rt][ct][i] = sc;
                ((float*)outv)[r * 256 + c] = sc;
            }
    int b_ = rowBase >> 10, tc_ = (rowBase >> 7) & 7;
#pragma unroll
    for (int ct = 0; ct < 2; ct++) {
        float m = vv[0][ct][0];
#pragma unroll
        for (int rt = 0; rt < 2; rt++)
#pragma unroll
            for (int i = 0; i < 4; i++) m = fmaxf(m, vv[rt][ct][i]);
        float S = 0.f;
#pragma unroll
        for (int rt = 0; rt < 2; rt++)
#pragma unroll
            for (int i = 0; i < 4; i++) S += __expf(vv[rt][ct][i] - m);
#pragma unroll
        for (int o = 16; o <= 32; o <<= 1) {
            float om = __shfl_xor(m, o, 64);
            float oS = __shfl_xor(S, o, 64);
            float nm = fmaxf(m, om);
            S = S * __expf(m - nm) + oS * __expf(om - nm);
            m = nm;
        }
        if (grp == 0) {
            sredm[wid][ct][l15] = m;
            sredS[wid][ct][l15] = S;
        }
    }
    __syncthreads();
    if (tid < 64) {
        int cl = tid;
        int wcol = cl >> 5, ct = (cl >> 4) & 1, k15 = cl & 15;
        float m = -1e30f, S = 0.f;
#pragma unroll
        for (int rg = 0; rg < 4; rg++) {
            float om = sredm[rg * 2 + wcol][ct][k15];
            float oS = sredS[rg * 2 + wcol][ct][k15];
            float nm = fmaxf(m, om);
            S = S * __expf(m - nm) + oS * __expf(om - nm);
            m = nm;
        }
        int idx = (b_ * 8 + tc_) * Hh + colBase + cl;
        pms[idx * 2] = m;
        pms[idx * 2 + 1] = S;
    }
}

// ---------- softmax pass 2: combine partials, emit ctx (bf16) and x_attn ----------
__global__ __launch_bounds__(256) void softmax_pass2(const float* __restrict__ scores,
                                                     const float* __restrict__ partMS,
                                                     unsigned short* __restrict__ ctx,
                                                     float* __restrict__ x_attn) {
    int b = blockIdx.x, tc = blockIdx.y;
    int tid = threadIdx.x, w = tid >> 6, lane = tid & 63;
    float mj[4], Sj[4];
#pragma unroll
    for (int j = 0; j < 4; j++) {
        int k = lane + j * 64;
        float m = -1e30f;
#pragma unroll
        for (int c = 0; c < 8; c++)
            m = fmaxf(m, partMS[((b * 8 + c) * Hh + k) * 2]);
        float S = 0.f;
#pragma unroll
        for (int c = 0; c < 8; c++) {
            int idx = (b * 8 + c) * Hh + k;
            S += partMS[idx * 2 + 1] * __expf(partMS[idx * 2] - m);
        }
        mj[j] = m;
        Sj[j] = 1.f / S;
    }
    for (int i = 0; i < 32; i++) {
        int t = tc * 128 + w * 32 + i;
        const float* sp = scores + ((size_t)b * Tt + t) * Hh;
        unsigned short* cp = ctx + ((size_t)b * Tt + t) * Hh;
        float accsm = 0.f;
#pragma unroll
        for (int j = 0; j < 4; j++) {
            int k = lane + j * 64;
            float s = sp[k];
            float sm = __expf(s - mj[j]) * Sj[j];
            accsm += sm;
            cp[k] = f2bf(s * sm);
        }
#pragma unroll
        for (int o = 32; o >= 1; o >>= 1) accsm += __shfl_xor(accsm, o, 64);
        if (lane == 0) x_attn[b * Tt + t] = accsm;
    }
}

// ---------- GRU scan (R14: barrier-free, per-wave LDS flag sync) ----------
// R13 post-mortem: all-AGPR == wn-in-LDS (1197us both) -> the ~950cy/step
// above the 1862cy MFMA-issue floor is the SERIAL TAIL (post-barrier ds_read
// latency + gate chain + barrier reconvergence), serialized by __syncthreads.
// R14: producer-consumer flags. Wave w owns h-chunk w (cols 32w..32w+31);
// after its epilogue it writes hb[t&1], drains lgkm, sets flagv[w]=t
// (volatile LDS). Consumers process K-chunks in ROTATED order kc=(w+i)&7 --
// own chunk first (no wait), so each foreign chunk has >=116cy of MFMA slack.
// Skew is self-bounded at 1 step (a wave needs all flags>=t-1 to proceed),
// exactly matching the 2-buffer hb parity -> no WAR race. Tail now overlaps
// other waves' MFMA issue.
#define HBPAD 28672  // u16 elems per buffer; 2*28672*2B = 112 KB LDS (1 WG/CU)
__global__ __attribute__((amdgpu_flat_work_group_size(512, 512),
                          amdgpu_waves_per_eu(2, 2)))
void scan_gru(
    const unsigned short* __restrict__ xg,
    const float* __restrict__ whr, const float* __restrict__ whz, const float* __restrict__ whn,
    const float* __restrict__ bhn,
    const float* __restrict__ hidden,
    float* __restrict__ outputs, float* __restrict__ hlast) {
    __shared__ __align__(16) unsigned short hb[2][HBPAD];  // h dbuf; tail = occupancy limiter
    // flags live in hb[0]'s pad area (offset 1KB, untouched by h data)
    volatile int* flagv = (volatile int*)&hb[0][512];
    int b = blockIdx.x;
    int tid = threadIdx.x, w = tid >> 6, lane = tid & 63;
    int grp = lane >> 4;

    // weight fragments: wave owns cols [32w,32w+32) of all 3 matrices
    u16x8 wfr[2][8], wfz[2][8], wfn[2][8];
#pragma unroll
    for (int ct = 0; ct < 2; ct++) {
        int col = w * 32 + ct * 16 + (lane & 15);
#pragma unroll
        for (int kc = 0; kc < 8; kc++) {
            const float* s1 = whr + (size_t)col * Hh + kc * 32 + grp * 8;
            wfr[ct][kc] = pack8(*(const float4*)s1, *(const float4*)(s1 + 4));
            const float* s2 = whz + (size_t)col * Hh + kc * 32 + grp * 8;
            wfz[ct][kc] = pack8(*(const float4*)s2, *(const float4*)(s2 + 4));
            const float* s3 = whn + (size_t)col * Hh + kc * 32 + grp * 8;
            wfn[ct][kc] = pack8(*(const float4*)s3, *(const float4*)(s3 + 4));
        }
    }
    // Coax all 48 fragments (192 regs) into the AGPR half (R8-R10 verified).
    asm volatile("" : "+a"(wfr[0][0]), "+a"(wfr[0][1]), "+a"(wfr[0][2]), "+a"(wfr[0][3]),
                      "+a"(wfr[0][4]), "+a"(wfr[0][5]), "+a"(wfr[0][6]), "+a"(wfr[0][7]));
    asm volatile("" : "+a"(wfr[1][0]), "+a"(wfr[1][1]), "+a"(wfr[1][2]), "+a"(wfr[1][3]),
                      "+a"(wfr[1][4]), "+a"(wfr[1][5]), "+a"(wfr[1][6]), "+a"(wfr[1][7]));
    asm volatile("" : "+a"(wfz[0][0]), "+a"(wfz[0][1]), "+a"(wfz[0][2]), "+a"(wfz[0][3]),
                      "+a"(wfz[0][4]), "+a"(wfz[0][5]), "+a"(wfz[0][6]), "+a"(wfz[0][7]));
    asm volatile("" : "+a"(wfz[1][0]), "+a"(wfz[1][1]), "+a"(wfz[1][2]), "+a"(wfz[1][3]),
                      "+a"(wfz[1][4]), "+a"(wfz[1][5]), "+a"(wfz[1][6]), "+a"(wfz[1][7]));
    asm volatile("" : "+a"(wfn[0][0]), "+a"(wfn[0][1]), "+a"(wfn[0][2]), "+a"(wfn[0][3]),
                      "+a"(wfn[0][4]), "+a"(wfn[0][5]), "+a"(wfn[0][6]), "+a"(wfn[0][7]));
    asm volatile("" : "+a"(wfn[1][0]), "+a"(wfn[1][1]), "+a"(wfn[1][2]), "+a"(wfn[1][3]),
                      "+a"(wfn[1][4]), "+a"(wfn[1][5]), "+a"(wfn[1][6]), "+a"(wfn[1][7]));

    // per-lane state: lanes 0-15 own col-tile0, lanes 16-31 own col-tile1
    int mycol = w * 32 + (lane & 31);
    float bhnS = 0.f, hpS = 0.f;
    if (lane < 32) {
        bhnS = bhn[mycol];
        hpS = hidden[b * Hh + mycol];
        hb[0][mycol] = f2bf(hpS);
        outputs[((size_t)b * Tt) * Hh + mycol] = hpS;  // outputs[:,0,:] = h0 exact
    }
    if (tid < 8) flagv[tid] = 0;  // flag[w]=0 <=> h(0) chunk w available in hb[0]
    const unsigned short* xr = xg;
    const unsigned short* xz = xg + 16777216;
    const unsigned short* xn = xg + 33554432;
    unsigned short pxr = 0, pxz = 0, pxn = 0;
    if (lane < 32) {
        size_t off = ((size_t)b * Tt + 1) * Hh + mycol;  // t=1
        pxr = xr[off]; pxz = xz[off]; pxn = xn[off];
    }
    __syncthreads();  // one-time: h0 + flags visible

    for (int t = 1; t < Tt; t++) {
        int rp = (t - 1) & 1;   // read parity
        unsigned short cxr = pxr, cxz = pxz, cxn = pxn;
        int tnext = (t + 1 < Tt) ? t + 1 : t;
        if (lane < 32) {  // prefetch next step (latency hidden under MFMAs)
            size_t off = ((size_t)b * Tt + tnext) * Hh + mycol;
            pxr = xr[off]; pxz = xz[off]; pxn = xn[off];
        }
        f32x4 ar0 = {0.f, 0.f, 0.f, 0.f}, ar1 = {0.f, 0.f, 0.f, 0.f};
        f32x4 az0 = {0.f, 0.f, 0.f, 0.f}, az1 = {0.f, 0.f, 0.f, 0.f};
        f32x4 an0 = {0.f, 0.f, 0.f, 0.f}, an1 = {0.f, 0.f, 0.f, 0.f};
#pragma unroll
        for (int i = 0; i < 8; i++) {
            int kc = (w + i) & 7;   // own chunk first; foreign chunks deferred
            if (i > 0) {
                while (flagv[kc] < t - 1) __builtin_amdgcn_s_sleep(1);
                asm volatile("" ::: "memory");  // pin chunk read after the poll
            }
            u16x8 af = *(const u16x8*)&hb[rp][kc * 32 + grp * 8];  // broadcast read
            ar0 = mfma16(af, wfr[0][kc], ar0);
            ar1 = mfma16(af, wfr[1][kc], ar1);
            az0 = mfma16(af, wfz[0][kc], az0);
            az1 = mfma16(af, wfz[1][kc], az1);
            an0 = mfma16(af, wfn[0][kc], an0);
            an1 = mfma16(af, wfn[1][kc], an1);
        }
        // all D rows identical -> lanes 16-31's reg0 of *1 accs hold tile1 cols
        float gr = (lane < 16) ? ar0[0] : ar1[0];
        float gz = (lane < 16) ? az0[0] : az1[0];
        float gn = (lane < 16) ? an0[0] : an1[0];
        if (lane < 32) {
            float r0 = sigm(bf2f(cxr) + gr);              // b_ir+b_hr pre-folded
            float z0 = sigm(bf2f(cxz) + gz);              // b_iz+b_hz pre-folded
            float n0 = tanh_f(bf2f(cxn) + r0 * (gn + bhnS));
            float hn = (1.f - z0) * n0 + z0 * hpS;
            hb[t & 1][mycol] = f2bf(hn);
            outputs[((size_t)b * Tt + t) * Hh + mycol] = hn;  // fire-and-forget
            hpS = hn;
        }
        // h-chunk write visible before flag set (LDS-only drain; vmcnt untouched)
        asm volatile("s_waitcnt lgkmcnt(0)" ::: "memory");
        if (lane == 0) flagv[w] = t;
    }
    if (lane < 32) {
        hlast[b * Hh + mycol] = hpS;
    }
}

// ---------- launch ----------
extern "C" void kernel_launch(void* const* d_in, const int* in_sizes, int n_in,
                              void* d_out, int out_size, void* d_ws, size_t ws_size,
                              hipStream_t stream) {
    const float* inputs = (const float*)d_in[0];
    const float* hidden = (const float*)d_in[1];
    const float* W_w  = (const float*)d_in[2];
    const float* W_b  = (const float*)d_in[3];
    const float* V_w  = (const float*)d_in[4];
    const float* V_b  = (const float*)d_in[5];
    const float* w_ir = (const float*)d_in[6];
    const float* w_iz = (const float*)d_in[7];
    const float* w_in = (const float*)d_in[8];
    const float* b_ir = (const float*)d_in[9];
    const float* b_iz = (const float*)d_in[10];
    const float* b_in = (const float*)d_in[11];
    const float* w_hr = (const float*)d_in[12];
    const float* w_hz = (const float*)d_in[13];
    const float* w_hn = (const float*)d_in[14];
    const float* b_hr = (const float*)d_in[15];
    const float* b_hz = (const float*)d_in[16];
    const float* b_hn = (const float*)d_in[17];

    // workspace layout (~129.3 MB)
    float* hp = (float*)d_ws;                                  // 65536 f32
    float* partMS = hp + 65536;                                // 64*8*256*2 f32
    float* cbias = partMS + 262144;                            // 512 f32
    unsigned short* zbuf = (unsigned short*)(cbias + 512);     // 16.7M bf16
    unsigned short* ctx = zbuf;                                // alias: z dead after GEMM2
    unsigned short* xgb = zbuf + 16777216;                     // 3 x 16.7M bf16

    float* scores  = (float*)d_out;         // scores staged in outputs slot (dead before scan)
    float* outputs = (float*)d_out;
    float* hlast   = outputs + 16777216;
    float* x_attn  = hlast + 16384;

    hp_kernel<<<64, 256, 0, stream>>>(hidden, W_w, b_ir, b_hr, b_iz, b_hz, hp, cbias);

    gemm128<0, false><<<dim3(512, 2), 512, 0, stream>>>(
        inputs, W_w, nullptr, nullptr, 512, 256,
        nullptr, nullptr, nullptr, hp, W_b, zbuf);

    // GEMM2 with fused softmax pass1 (writes scores + partMS)
    gemm_k1<<<dim3(512, 4), 512, 0, stream>>>(
        zbuf, V_w, 256, 0, V_b, partMS, scores);

    softmax_pass2<<<dim3(64, 8), 256, 0, stream>>>(scores, partMS, ctx, x_attn);

    gemm128<2, true><<<dim3(512, 6), 512, 0, stream>>>(
        ctx, w_ir, w_iz, w_in, 256, 0,
        cbias, cbias + 256, b_in, nullptr, nullptr, xgb);

    scan_gru<<<64, 512, 0, stream>>>(
        xgb, w_hr, w_hz, w_hn, b_hn, hidden, outputs, hlast);
}

// Round 15
// 1373.049 us; speedup vs baseline: 7.3279x; 7.3279x over previous
//
#include <hip/hip_runtime.h>

#define DEVI __device__ __forceinline__

typedef float  f32x4  __attribute__((ext_vector_type(4)));
typedef __bf16 bf16x8 __attribute__((ext_vector_type(8)));
typedef unsigned short u16x8 __attribute__((ext_vector_type(8)));

// ---------- helpers ----------
DEVI unsigned short f2bf(float f) {
    unsigned u = __builtin_bit_cast(unsigned, f);
    unsigned r = (u + 0x7fffu + ((u >> 16) & 1u)) >> 16;
    return (unsigned short)r;
}
DEVI float bf2f(unsigned short s) {
    return __builtin_bit_cast(float, (unsigned)s << 16);
}
DEVI u16x8 pack8(float4 a, float4 b) {
    u16x8 p;
    p[0] = f2bf(a.x); p[1] = f2bf(a.y); p[2] = f2bf(a.z); p[3] = f2bf(a.w);
    p[4] = f2bf(b.x); p[5] = f2bf(b.y); p[6] = f2bf(b.z); p[7] = f2bf(b.w);
    return p;
}
DEVI f32x4 mfma16(u16x8 a, u16x8 b, f32x4 c) {
    return __builtin_amdgcn_mfma_f32_16x16x32_bf16(
        __builtin_bit_cast(bf16x8, a), __builtin_bit_cast(bf16x8, b), c, 0, 0, 0);
}
DEVI float sigm(float x)   { return 1.f / (1.f + __expf(-x)); }
DEVI float tanh_f(float x) { return 1.f - 2.f / (1.f + __expf(2.f * x)); }

// dims
#define Hh 256
#define Bb 64
#define Tt 1024

// ---------- K0: hp[b][k] = hidden[b] . W_w[k][0:256]; block 0 also folds biases ----------
__global__ __launch_bounds__(256) void hp_kernel(const float* __restrict__ hid,
                                                 const float* __restrict__ Ww,
                                                 const float* __restrict__ b_ir,
                                                 const float* __restrict__ b_hr,
                                                 const float* __restrict__ b_iz,
                                                 const float* __restrict__ b_hz,
                                                 float* __restrict__ hp,
                                                 float* __restrict__ cb) {
    int b = blockIdx.x, k = threadIdx.x;
    if (b == 0) {  // fused bias_prep (saves a launch)
        cb[k] = b_ir[k] + b_hr[k];
        cb[256 + k] = b_iz[k] + b_hz[k];
    }
    __shared__ __align__(16) float hs[Hh];
    hs[k] = hid[b * Hh + k];
    __syncthreads();
    const float4* w4 = (const float4*)(Ww + (size_t)k * 512);
    const float4* h4 = (const float4*)hs;
    float acc = 0.f;
#pragma unroll 8
    for (int i = 0; i < 64; i++) {
        float4 a = w4[i], x = h4[i];
        acc += a.x * x.x + a.y * x.y + a.z * x.z + a.w * x.w;
    }
    hp[b * Hh + k] = acc;
}

// ---------- GEMM 128x128 tile (EPI0 / EPI2): 8 waves in 2x4, 512 MFMA/block ----------
// EPI 0: z = tanh(acc + hp[b][c] + W_b[c]) -> bf16 [r][c]
// EPI 2: xproj = acc + b_i[c] -> bf16 [mat][r][c]  (r = b*1024+t)
template <int EPI, bool ABF16>
__global__ __launch_bounds__(512) void gemm128(
    const void* __restrict__ Aab,
    const float* __restrict__ W0, const float* __restrict__ W1, const float* __restrict__ W2,
    int wstride, int wcoloff,
    const float* __restrict__ bv0, const float* __restrict__ bv1, const float* __restrict__ bv2,
    const float* __restrict__ hp, const float* __restrict__ Wb,
    void* __restrict__ outv) {
    __shared__ __align__(16) unsigned short As[128 * 256];  // 64KB
    __shared__ __align__(16) unsigned short Bs[128 * 256];  // 64KB (128KB total: 1 WG/CU)

    int tid = threadIdx.x;
    int bx = blockIdx.x, by = blockIdx.y;
    int mat = (EPI == 2) ? (by >> 1) : 0;
    int cb  = (EPI == 2) ? (by & 1) : by;
    int rowBase = bx * 128, colBase = cb * 128;
    const float* W  = (mat == 0) ? W0 : ((mat == 1) ? W1 : W2);
    const float* bv = (mat == 0) ? bv0 : ((mat == 1) ? bv1 : bv2);

    // stage A: 128 rows x 32 chunks(16B), swizzled g ^= (r&7)
    if (ABF16) {
        const unsigned short* A = (const unsigned short*)Aab;
#pragma unroll
        for (int i = 0; i < 8; i++) {
            int idx = i * 512 + tid, r = idx >> 5, g = idx & 31, gs = g ^ (r & 7);
            *(uint4*)&As[r * 256 + gs * 8] =
                *(const uint4*)(A + (((size_t)(rowBase + r)) << 8) + g * 8);
        }
    } else {
        const float* A = (const float*)Aab;
#pragma unroll
        for (int i = 0; i < 8; i++) {
            int idx = i * 512 + tid, r = idx >> 5, g = idx & 31, gs = g ^ (r & 7);
            const float* s = A + (((size_t)(rowBase + r)) << 8) + g * 8;
            float4 f0 = *(const float4*)s, f1 = *(const float4*)(s + 4);
            *(u16x8*)&As[r * 256 + gs * 8] = pack8(f0, f1);
        }
    }
    // stage B: 128 W-rows (output cols) x 32 chunks
#pragma unroll
    for (int i = 0; i < 8; i++) {
        int idx = i * 512 + tid, r = idx >> 5, g = idx & 31, gs = g ^ (r & 7);
        const float* s = W + (size_t)(colBase + r) * wstride + wcoloff + g * 8;
        float4 f0 = *(const float4*)s, f1 = *(const float4*)(s + 4);
        *(u16x8*)&Bs[r * 256 + gs * 8] = pack8(f0, f1);
    }
    __syncthreads();

    int wid = tid >> 6, lane = tid & 63, l15 = lane & 15, grp = lane >> 4;
    int wr = (wid >> 2) * 64, wc = (wid & 3) * 32;   // wave tile: 64 rows x 32 cols
    f32x4 acc[4][2] = {};
#pragma unroll
    for (int kc = 0; kc < 8; kc++) {
        u16x8 a[4], bb[2];
#pragma unroll
        for (int rt = 0; rt < 4; rt++) {
            int r = wr + rt * 16 + l15;
            int gs = (kc * 4 + grp) ^ (r & 7);
            a[rt] = *(const u16x8*)&As[r * 256 + gs * 8];
        }
#pragma unroll
        for (int ct = 0; ct < 2; ct++) {
            int r = wc + ct * 16 + l15;
            int gs = (kc * 4 + grp) ^ (r & 7);
            bb[ct] = *(const u16x8*)&Bs[r * 256 + gs * 8];
        }
#pragma unroll
        for (int rt = 0; rt < 4; rt++)
#pragma unroll
            for (int ct = 0; ct < 2; ct++)
                acc[rt][ct] = mfma16(a[rt], bb[ct], acc[rt][ct]);
    }
    // epilogue: D row = (lane>>4)*4 + i, col = lane&15
#pragma unroll
    for (int rt = 0; rt < 4; rt++)
#pragma unroll
        for (int ct = 0; ct < 2; ct++)
#pragma unroll
            for (int i = 0; i < 4; i++) {
                int rl = wr + rt * 16 + grp * 4 + i;
                int cl = wc + ct * 16 + l15;
                size_t r = (size_t)rowBase + rl;
                int c = colBase + cl;
                float v = acc[rt][ct][i];
                if (EPI == 0) {
                    v = tanh_f(v + hp[(r >> 10) * 256 + c] + Wb[c]);
                    ((unsigned short*)outv)[r * 256 + c] = f2bf(v);
                } else {
                    ((unsigned short*)outv)[(size_t)mat * 16777216 + r * 256 + c] =
                        f2bf(v + bv[c]);
                }
            }
}

// ---------- GEMM 128x64 (EPI1 only): scores + fused softmax pass1 ----------
__global__ __launch_bounds__(512) void gemm_k1(
    const void* __restrict__ Aab,
    const float* __restrict__ W0, int wstride, int wcoloff,
    const float* __restrict__ bv0,
    float* __restrict__ pms,
    void* __restrict__ outv) {
    __shared__ __align__(16) unsigned short As[128 * 256];
    __shared__ __align__(16) unsigned short Bs[64 * 256];
    __shared__ float sredm[8][2][16], sredS[8][2][16];

    int tid = threadIdx.x;
    int bx = blockIdx.x, by = blockIdx.y;
    int rowBase = bx * 128, colBase = by * 64;
    const float* W = W0;
    const float* bv = bv0;

    const unsigned short* A = (const unsigned short*)Aab;
#pragma unroll
    for (int i = 0; i < 8; i++) {
        int idx = i * 512 + tid, r = idx >> 5, g = idx & 31, gs = g ^ (r & 7);
        *(uint4*)&As[r * 256 + gs * 8] =
            *(const uint4*)(A + (((size_t)(rowBase + r)) << 8) + g * 8);
    }
#pragma unroll
    for (int i = 0; i < 4; i++) {
        int idx = i * 512 + tid, r = idx >> 5, g = idx & 31, gs = g ^ (r & 7);
        const float* s = W + (size_t)(colBase + r) * wstride + wcoloff + g * 8;
        float4 f0 = *(const float4*)s, f1 = *(const float4*)(s + 4);
        *(u16x8*)&Bs[r * 256 + gs * 8] = pack8(f0, f1);
    }
    __syncthreads();

    int wid = tid >> 6, lane = tid & 63, l15 = lane & 15, grp = lane >> 4;
    int wr = (wid >> 1) * 32, wc = (wid & 1) * 32;
    f32x4 acc[2][2] = {};
#pragma unroll
    for (int kc = 0; kc < 8; kc++) {
        u16x8 a[2], bb[2];
#pragma unroll
        for (int rt = 0; rt < 2; rt++) {
            int r = wr + rt * 16 + l15;
            int gs = (kc * 4 + grp) ^ (r & 7);
            a[rt] = *(const u16x8*)&As[r * 256 + gs * 8];
        }
#pragma unroll
        for (int ct = 0; ct < 2; ct++) {
            int r = wc + ct * 16 + l15;
            int gs = (kc * 4 + grp) ^ (r & 7);
            bb[ct] = *(const u16x8*)&Bs[r * 256 + gs * 8];
        }
#pragma unroll
        for (int rt = 0; rt < 2; rt++)
#pragma unroll
            for (int ct = 0; ct < 2; ct++)
                acc[rt][ct] = mfma16(a[rt], bb[ct], acc[rt][ct]);
    }
    float vv[2][2][4];
#pragma unroll
    for (int rt = 0; rt < 2; rt++)
#pragma unroll
        for (int ct = 0; ct < 2; ct++)
#pragma unroll
            for (int i = 0; i < 4; i++) {
                int rl = wr + rt * 16 + grp * 4 + i;
                int cl = wc + ct * 16 + l15;
                size_t r = (size_t)rowBase + rl;
                int c = colBase + cl;
                float sc = acc[rt][ct][i] + bv[c];
                vv[rt][ct][i] = sc;
                ((float*)outv)[r * 256 + c] = sc;
            }
    // fused softmax pass1: per-col (max, sumexp) over this block's 128 rows
    int b_ = rowBase >> 10, tc_ = (rowBase >> 7) & 7;
#pragma unroll
    for (int ct = 0; ct < 2; ct++) {
        float m = vv[0][ct][0];
#pragma unroll
        for (int rt = 0; rt < 2; rt++)
#pragma unroll
            for (int i = 0; i < 4; i++) m = fmaxf(m, vv[rt][ct][i]);
        float S = 0.f;
#pragma unroll
        for (int rt = 0; rt < 2; rt++)
#pragma unroll
            for (int i = 0; i < 4; i++) S += __expf(vv[rt][ct][i] - m);
#pragma unroll
        for (int o = 16; o <= 32; o <<= 1) {
            float om = __shfl_xor(m, o, 64);
            float oS = __shfl_xor(S, o, 64);
            float nm = fmaxf(m, om);
            S = S * __expf(m - nm) + oS * __expf(om - nm);
            m = nm;
        }
        if (grp == 0) {
            sredm[wid][ct][l15] = m;
            sredS[wid][ct][l15] = S;
        }
    }
    __syncthreads();
    if (tid < 64) {
        int cl = tid;
        int wcol = cl >> 5, ct = (cl >> 4) & 1, k15 = cl & 15;
        float m = -1e30f, S = 0.f;
#pragma unroll
        for (int rg = 0; rg < 4; rg++) {
            float om = sredm[rg * 2 + wcol][ct][k15];
            float oS = sredS[rg * 2 + wcol][ct][k15];
            float nm = fmaxf(m, om);
            S = S * __expf(m - nm) + oS * __expf(om - nm);
            m = nm;
        }
        int idx = (b_ * 8 + tc_) * Hh + colBase + cl;
        pms[idx * 2] = m;
        pms[idx * 2 + 1] = S;
    }
}

// ---------- softmax pass 2: combine partials, emit ctx (bf16) and x_attn ----------
__global__ __launch_bounds__(256) void softmax_pass2(const float* __restrict__ scores,
                                                     const float* __restrict__ partMS,
                                                     unsigned short* __restrict__ ctx,
                                                     float* __restrict__ x_attn) {
    int b = blockIdx.x, tc = blockIdx.y;
    int tid = threadIdx.x, w = tid >> 6, lane = tid & 63;
    float mj[4], Sj[4];
#pragma unroll
    for (int j = 0; j < 4; j++) {
        int k = lane + j * 64;
        float m = -1e30f;
#pragma unroll
        for (int c = 0; c < 8; c++)
            m = fmaxf(m, partMS[((b * 8 + c) * Hh + k) * 2]);
        float S = 0.f;
#pragma unroll
        for (int c = 0; c < 8; c++) {
            int idx = (b * 8 + c) * Hh + k;
            S += partMS[idx * 2 + 1] * __expf(partMS[idx * 2] - m);
        }
        mj[j] = m;
        Sj[j] = 1.f / S;
    }
    for (int i = 0; i < 32; i++) {
        int t = tc * 128 + w * 32 + i;
        const float* sp = scores + ((size_t)b * Tt + t) * Hh;
        unsigned short* cp = ctx + ((size_t)b * Tt + t) * Hh;
        float accsm = 0.f;
#pragma unroll
        for (int j = 0; j < 4; j++) {
            int k = lane + j * 64;
            float s = sp[k];
            float sm = __expf(s - mj[j]) * Sj[j];
            accsm += sm;
            cp[k] = f2bf(s * sm);
        }
#pragma unroll
        for (int o = 32; o >= 1; o >>= 1) accsm += __shfl_xor(accsm, o, 64);
        if (lane == 0) x_attn[b * Tt + t] = accsm;
    }
}

// ---------- GRU scan (R13 config restored -- proven best: 1197us) ----------
// R14 post-mortem: LDS flag-sync poll inside the K-loop broke the AGPR
// allocation (VGPR 128->116, WRITE_SIZE +37MB spill signature) and s_sleep
// polling serialized waves -> 10ms. REVERTED to R13: all weights in AGPR
// (192 wf + 24 acc, empty-asm coax), af read in-loop, shfl-free epilogue,
// one lgkmcnt-only barrier per step. The remaining ~1000cy/step above the
// 1862cy MFMA-issue floor is the recurrence's serial tail (MFMA drain +
// gate chain + barrier + ds_read latency) -- structural for this algorithm.
#define HBPAD 28672  // u16 elems per buffer; 2*28672*2B = 112 KB LDS (1 WG/CU)
__global__ __attribute__((amdgpu_flat_work_group_size(512, 512),
                          amdgpu_waves_per_eu(2, 2)))
void scan_gru(
    const unsigned short* __restrict__ xg,
    const float* __restrict__ whr, const float* __restrict__ whz, const float* __restrict__ whn,
    const float* __restrict__ bhn,
    const float* __restrict__ hidden,
    float* __restrict__ outputs, float* __restrict__ hlast) {
    __shared__ __align__(16) unsigned short hb[2][HBPAD];  // h dbuf; rest = occupancy limiter
    int b = blockIdx.x;
    int tid = threadIdx.x, w = tid >> 6, lane = tid & 63;
    int grp = lane >> 4;

    // weight fragments: wave owns cols [32w,32w+32) of all 3 matrices
    u16x8 wfr[2][8], wfz[2][8], wfn[2][8];
#pragma unroll
    for (int ct = 0; ct < 2; ct++) {
        int col = w * 32 + ct * 16 + (lane & 15);
#pragma unroll
        for (int kc = 0; kc < 8; kc++) {
            const float* s1 = whr + (size_t)col * Hh + kc * 32 + grp * 8;
            wfr[ct][kc] = pack8(*(const float4*)s1, *(const float4*)(s1 + 4));
            const float* s2 = whz + (size_t)col * Hh + kc * 32 + grp * 8;
            wfz[ct][kc] = pack8(*(const float4*)s2, *(const float4*)(s2 + 4));
            const float* s3 = whn + (size_t)col * Hh + kc * 32 + grp * 8;
            wfn[ct][kc] = pack8(*(const float4*)s3, *(const float4*)(s3 + 4));
        }
    }
    // Coax all 48 fragments (192 regs) into the AGPR half (R8-R10 verified).
    asm volatile("" : "+a"(wfr[0][0]), "+a"(wfr[0][1]), "+a"(wfr[0][2]), "+a"(wfr[0][3]),
                      "+a"(wfr[0][4]), "+a"(wfr[0][5]), "+a"(wfr[0][6]), "+a"(wfr[0][7]));
    asm volatile("" : "+a"(wfr[1][0]), "+a"(wfr[1][1]), "+a"(wfr[1][2]), "+a"(wfr[1][3]),
                      "+a"(wfr[1][4]), "+a"(wfr[1][5]), "+a"(wfr[1][6]), "+a"(wfr[1][7]));
    asm volatile("" : "+a"(wfz[0][0]), "+a"(wfz[0][1]), "+a"(wfz[0][2]), "+a"(wfz[0][3]),
                      "+a"(wfz[0][4]), "+a"(wfz[0][5]), "+a"(wfz[0][6]), "+a"(wfz[0][7]));
    asm volatile("" : "+a"(wfz[1][0]), "+a"(wfz[1][1]), "+a"(wfz[1][2]), "+a"(wfz[1][3]),
                      "+a"(wfz[1][4]), "+a"(wfz[1][5]), "+a"(wfz[1][6]), "+a"(wfz[1][7]));
    asm volatile("" : "+a"(wfn[0][0]), "+a"(wfn[0][1]), "+a"(wfn[0][2]), "+a"(wfn[0][3]),
                      "+a"(wfn[0][4]), "+a"(wfn[0][5]), "+a"(wfn[0][6]), "+a"(wfn[0][7]));
    asm volatile("" : "+a"(wfn[1][0]), "+a"(wfn[1][1]), "+a"(wfn[1][2]), "+a"(wfn[1][3]),
                      "+a"(wfn[1][4]), "+a"(wfn[1][5]), "+a"(wfn[1][6]), "+a"(wfn[1][7]));

    // per-lane state: lanes 0-15 own col-tile0, lanes 16-31 own col-tile1
    int mycol = w * 32 + (lane & 31);
    float bhnS = 0.f, hpS = 0.f;
    if (lane < 32) {
        bhnS = bhn[mycol];
        hpS = hidden[b * Hh + mycol];
        hb[0][mycol] = f2bf(hpS);
        outputs[((size_t)b * Tt) * Hh + mycol] = hpS;  // outputs[:,0,:] = h0 exact
    }
    const unsigned short* xr = xg;
    const unsigned short* xz = xg + 16777216;
    const unsigned short* xn = xg + 33554432;
    unsigned short pxr = 0, pxz = 0, pxn = 0;
    if (lane < 32) {
        size_t off = ((size_t)b * Tt + 1) * Hh + mycol;  // t=1
        pxr = xr[off]; pxz = xz[off]; pxn = xn[off];
    }
    __syncthreads();

    int p = 0;
    for (int t = 1; t < Tt; t++) {
        unsigned short cxr = pxr, cxz = pxz, cxn = pxn;
        int tnext = (t + 1 < Tt) ? t + 1 : t;
        if (lane < 32) {  // prefetch next step (latency hidden under MFMAs)
            size_t off = ((size_t)b * Tt + tnext) * Hh + mycol;
            pxr = xr[off]; pxz = xz[off]; pxn = xn[off];
        }
        f32x4 ar0 = {0.f, 0.f, 0.f, 0.f}, ar1 = {0.f, 0.f, 0.f, 0.f};
        f32x4 az0 = {0.f, 0.f, 0.f, 0.f}, az1 = {0.f, 0.f, 0.f, 0.f};
        f32x4 an0 = {0.f, 0.f, 0.f, 0.f}, an1 = {0.f, 0.f, 0.f, 0.f};
#pragma unroll
        for (int kc = 0; kc < 8; kc++) {
            u16x8 af = *(const u16x8*)&hb[p][kc * 32 + grp * 8];  // broadcast read
            ar0 = mfma16(af, wfr[0][kc], ar0);
            ar1 = mfma16(af, wfr[1][kc], ar1);
            az0 = mfma16(af, wfz[0][kc], az0);
            az1 = mfma16(af, wfz[1][kc], az1);
            an0 = mfma16(af, wfn[0][kc], an0);
            an1 = mfma16(af, wfn[1][kc], an1);
        }
        // all D rows identical -> lanes 16-31's reg0 of *1 accs hold tile1 cols
        float gr = (lane < 16) ? ar0[0] : ar1[0];
        float gz = (lane < 16) ? az0[0] : az1[0];
        float gn = (lane < 16) ? an0[0] : an1[0];
        if (lane < 32) {
            float r0 = sigm(bf2f(cxr) + gr);              // b_ir+b_hr pre-folded
            float z0 = sigm(bf2f(cxz) + gz);              // b_iz+b_hz pre-folded
            float n0 = tanh_f(bf2f(cxn) + r0 * (gn + bhnS));
            float hn = (1.f - z0) * n0 + z0 * hpS;
            hb[p ^ 1][mycol] = f2bf(hn);   // write the OTHER buffer: no read-WAR
            outputs[((size_t)b * Tt + t) * Hh + mycol] = hn;  // fire-and-forget
            hpS = hn;
        }
        p ^= 1;
        // LDS-only barrier: do NOT drain vmcnt (stores + prefetch stay in flight).
        asm volatile("s_waitcnt lgkmcnt(0)" ::: "memory");
        __builtin_amdgcn_s_barrier();
        asm volatile("" ::: "memory");
    }
    if (lane < 32) {
        hlast[b * Hh + mycol] = hpS;
    }
}

// ---------- launch ----------
extern "C" void kernel_launch(void* const* d_in, const int* in_sizes, int n_in,
                              void* d_out, int out_size, void* d_ws, size_t ws_size,
                              hipStream_t stream) {
    const float* inputs = (const float*)d_in[0];
    const float* hidden = (const float*)d_in[1];
    const float* W_w  = (const float*)d_in[2];
    const float* W_b  = (const float*)d_in[3];
    const float* V_w  = (const float*)d_in[4];
    const float* V_b  = (const float*)d_in[5];
    const float* w_ir = (const float*)d_in[6];
    const float* w_iz = (const float*)d_in[7];
    const float* w_in = (const float*)d_in[8];
    const float* b_ir = (const float*)d_in[9];
    const float* b_iz = (const float*)d_in[10];
    const float* b_in = (const float*)d_in[11];
    const float* w_hr = (const float*)d_in[12];
    const float* w_hz = (const float*)d_in[13];
    const float* w_hn = (const float*)d_in[14];
    const float* b_hr = (const float*)d_in[15];
    const float* b_hz = (const float*)d_in[16];
    const float* b_hn = (const float*)d_in[17];

    // workspace layout (~129.3 MB)
    float* hp = (float*)d_ws;                                  // 65536 f32
    float* partMS = hp + 65536;                                // 64*8*256*2 f32
    float* cbias = partMS + 262144;                            // 512 f32
    unsigned short* zbuf = (unsigned short*)(cbias + 512);     // 16.7M bf16
    unsigned short* ctx = zbuf;                                // alias: z dead after GEMM2
    unsigned short* xgb = zbuf + 16777216;                     // 3 x 16.7M bf16

    float* scores  = (float*)d_out;         // scores staged in outputs slot (dead before scan)
    float* outputs = (float*)d_out;
    float* hlast   = outputs + 16777216;
    float* x_attn  = hlast + 16384;

    hp_kernel<<<64, 256, 0, stream>>>(hidden, W_w, b_ir, b_hr, b_iz, b_hz, hp, cbias);

    gemm128<0, false><<<dim3(512, 2), 512, 0, stream>>>(
        inputs, W_w, nullptr, nullptr, 512, 256,
        nullptr, nullptr, nullptr, hp, W_b, zbuf);

    // GEMM2 with fused softmax pass1 (writes scores + partMS)
    gemm_k1<<<dim3(512, 4), 512, 0, stream>>>(
        zbuf, V_w, 256, 0, V_b, partMS, scores);

    softmax_pass2<<<dim3(64, 8), 256, 0, stream>>>(scores, partMS, ctx, x_attn);

    gemm128<2, true><<<dim3(512, 6), 512, 0, stream>>>(
        ctx, w_ir, w_iz, w_in, 256, 0,
        cbias, cbias + 256, b_in, nullptr, nullptr, xgb);

    scan_gru<<<64, 512, 0, stream>>>(
        xgb, w_hr, w_hz, w_hn, b_hn, hidden, outputs, hlast);
}